// Round 1
// baseline (1443.040 us; speedup 1.0000x reference)
//
#include <hip/hip_runtime.h>
#include <math.h>

#define BATCH 4
#define SEQ   1024
#define EMB   1024
#define HEADS 16
#define HD    64
#define MTOT  (BATCH*SEQ)   // 4096

// ---------------- fp32 GEMM core: C = A @ W^T (+bias in epilogue) ----------
// A: (M x K) row-major, W: (N x K) row-major. 128x128 tile, BK=16, 256 thr,
// 8x8 micro-tile per thread.
#define GBM 128
#define GBN 128
#define GBK 16

__device__ __forceinline__ void gemm_tile(const float* __restrict__ A,
                                          const float* __restrict__ W,
                                          int K, int m0, int n0,
                                          float acc[8][8])
{
    __shared__ float As[GBK][GBM + 4];
    __shared__ float Bs[GBK][GBN + 4];
    const int tid = threadIdx.x;
#pragma unroll
    for (int i = 0; i < 8; ++i)
#pragma unroll
        for (int j = 0; j < 8; ++j) acc[i][j] = 0.f;

    const int nk = K / GBK;
    for (int kt = 0; kt < nk; ++kt) {
        __syncthreads();
#pragma unroll
        for (int i = 0; i < 2; ++i) {
            int idx = (tid << 1) + i;      // float4 index 0..511
            int r   = idx >> 2;            // 0..127
            int c   = (idx & 3) << 2;      // 0,4,8,12
            float4 va = *(const float4*)(A + (size_t)(m0 + r) * K + kt * GBK + c);
            As[c + 0][r] = va.x; As[c + 1][r] = va.y;
            As[c + 2][r] = va.z; As[c + 3][r] = va.w;
            float4 vb = *(const float4*)(W + (size_t)(n0 + r) * K + kt * GBK + c);
            Bs[c + 0][r] = vb.x; Bs[c + 1][r] = vb.y;
            Bs[c + 2][r] = vb.z; Bs[c + 3][r] = vb.w;
        }
        __syncthreads();
        const int tx = tid & 15, ty = tid >> 4;
#pragma unroll
        for (int kk = 0; kk < GBK; ++kk) {
            float4 a0 = *(const float4*)&As[kk][ty * 8];
            float4 a1 = *(const float4*)&As[kk][ty * 8 + 4];
            float4 b0 = *(const float4*)&Bs[kk][tx * 8];
            float4 b1 = *(const float4*)&Bs[kk][tx * 8 + 4];
            float av[8] = {a0.x, a0.y, a0.z, a0.w, a1.x, a1.y, a1.z, a1.w};
            float bv[8] = {b0.x, b0.y, b0.z, b0.w, b1.x, b1.y, b1.z, b1.w};
#pragma unroll
            for (int i = 0; i < 8; ++i)
#pragma unroll
                for (int j = 0; j < 8; ++j)
                    acc[i][j] = fmaf(av[i], bv[j], acc[i][j]);
        }
    }
}

// QKV projection: writes Q/K/V in (b, h, s, d) layout.
__global__ __launch_bounds__(256) void qkv_kernel(
    const float* __restrict__ x,
    const float* __restrict__ wq, const float* __restrict__ bq,
    const float* __restrict__ wk, const float* __restrict__ bk,
    const float* __restrict__ wv, const float* __restrict__ bv,
    float* __restrict__ qo, float* __restrict__ ko, float* __restrict__ vo)
{
    const float* Wm; const float* bias; float* outp;
    const int z = blockIdx.z;
    if (z == 0)      { Wm = wq; bias = bq; outp = qo; }
    else if (z == 1) { Wm = wk; bias = bk; outp = ko; }
    else             { Wm = wv; bias = bv; outp = vo; }
    const int m0 = blockIdx.y * GBM;
    const int n0 = blockIdx.x * GBN;
    float acc[8][8];
    gemm_tile(x, Wm, EMB, m0, n0, acc);
    const int tx = threadIdx.x & 15, ty = threadIdx.x >> 4;
#pragma unroll
    for (int i = 0; i < 8; ++i) {
        int m = m0 + ty * 8 + i;
        int b = m >> 10, s = m & (SEQ - 1);
#pragma unroll
        for (int j0 = 0; j0 < 8; j0 += 4) {
            int n = n0 + tx * 8 + j0;
            int h = n >> 6, d = n & 63;
            float4 v;
            v.x = acc[i][j0 + 0] + bias[n + 0];
            v.y = acc[i][j0 + 1] + bias[n + 1];
            v.z = acc[i][j0 + 2] + bias[n + 2];
            v.w = acc[i][j0 + 3] + bias[n + 3];
            *(float4*)(outp + ((size_t)(b * HEADS + h) * SEQ + s) * HD + d) = v;
        }
    }
}

// Output projection: out = ctx @ wo^T + bo, plain (M x E) row-major out.
__global__ __launch_bounds__(256) void oproj_kernel(
    const float* __restrict__ ctx, const float* __restrict__ wo,
    const float* __restrict__ bo, float* __restrict__ out)
{
    const int m0 = blockIdx.y * GBM;
    const int n0 = blockIdx.x * GBN;
    float acc[8][8];
    gemm_tile(ctx, wo, EMB, m0, n0, acc);
    const int tx = threadIdx.x & 15, ty = threadIdx.x >> 4;
#pragma unroll
    for (int i = 0; i < 8; ++i) {
        int m = m0 + ty * 8 + i;
#pragma unroll
        for (int j0 = 0; j0 < 8; j0 += 4) {
            int n = n0 + tx * 8 + j0;
            float4 v;
            v.x = acc[i][j0 + 0] + bo[n + 0];
            v.y = acc[i][j0 + 1] + bo[n + 1];
            v.z = acc[i][j0 + 2] + bo[n + 2];
            v.w = acc[i][j0 + 3] + bo[n + 3];
            *(float4*)(out + (size_t)m * EMB + n) = v;
        }
    }
}

// Attention: one block per (b*h, 16-row q-tile). Scores tile in LDS,
// softmax, write attn, then PV into ctx (merged (b,s,h*d) layout).
__global__ __launch_bounds__(256) void attn_kernel(
    const float* __restrict__ qws, const float* __restrict__ kws,
    const float* __restrict__ vws,
    float* __restrict__ attn, float* __restrict__ ctx)
{
    __shared__ float Qs[16][68];
    __shared__ float Ss[16][1028];
    __shared__ float KVs[64][68];
    const int bh  = blockIdx.x;     // 0..63 = b*16+h
    const int qt  = blockIdx.y;     // 0..63
    const int tid = threadIdx.x;
    const int qr  = tid >> 4;       // 0..15 (q row)
    const int tg  = tid & 15;       // 0..15 (col group)

    // load Q tile (16 x 64)
    {
        int r = tid >> 4, c = (tid & 15) << 2;
        *(float4*)&Qs[r][c] =
            *(const float4*)(qws + ((size_t)bh * SEQ + qt * 16 + r) * HD + c);
    }

    // scores = Q K^T * 0.125, streamed over 16 K-tiles of 64 rows
    for (int kt = 0; kt < 16; ++kt) {
        __syncthreads();
#pragma unroll
        for (int i = 0; i < 4; ++i) {
            int idx = tid + (i << 8);          // float4 idx 0..1023
            int r   = idx >> 4;                // 0..63
            int c   = (idx & 15) << 2;
            *(float4*)&KVs[r][c] =
                *(const float4*)(kws + ((size_t)bh * SEQ + kt * 64 + r) * HD + c);
        }
        __syncthreads();
        float s0 = 0.f, s1 = 0.f, s2 = 0.f, s3 = 0.f;
#pragma unroll
        for (int kk = 0; kk < 16; ++kk) {
            float4 q  = *(const float4*)&Qs[qr][kk * 4];
            float4 k0 = *(const float4*)&KVs[tg     ][kk * 4];
            float4 k1 = *(const float4*)&KVs[tg + 16][kk * 4];
            float4 k2 = *(const float4*)&KVs[tg + 32][kk * 4];
            float4 k3 = *(const float4*)&KVs[tg + 48][kk * 4];
            s0 = fmaf(q.x, k0.x, s0); s0 = fmaf(q.y, k0.y, s0);
            s0 = fmaf(q.z, k0.z, s0); s0 = fmaf(q.w, k0.w, s0);
            s1 = fmaf(q.x, k1.x, s1); s1 = fmaf(q.y, k1.y, s1);
            s1 = fmaf(q.z, k1.z, s1); s1 = fmaf(q.w, k1.w, s1);
            s2 = fmaf(q.x, k2.x, s2); s2 = fmaf(q.y, k2.y, s2);
            s2 = fmaf(q.z, k2.z, s2); s2 = fmaf(q.w, k2.w, s2);
            s3 = fmaf(q.x, k3.x, s3); s3 = fmaf(q.y, k3.y, s3);
            s3 = fmaf(q.z, k3.z, s3); s3 = fmaf(q.w, k3.w, s3);
        }
        int cb = kt * 64 + tg;
        Ss[qr][cb     ] = s0 * 0.125f;
        Ss[qr][cb + 16] = s1 * 0.125f;
        Ss[qr][cb + 32] = s2 * 0.125f;
        Ss[qr][cb + 48] = s3 * 0.125f;
    }

    // softmax over own columns (tg + 16*i), cross-lane reduce in width-16 groups
    float mx = -1e30f;
#pragma unroll
    for (int i = 0; i < 64; ++i) mx = fmaxf(mx, Ss[qr][tg + 16 * i]);
#pragma unroll
    for (int off = 1; off < 16; off <<= 1) mx = fmaxf(mx, __shfl_xor(mx, off, 16));
    float sum = 0.f;
#pragma unroll
    for (int i = 0; i < 64; ++i) {
        float p = __expf(Ss[qr][tg + 16 * i] - mx);
        Ss[qr][tg + 16 * i] = p;
        sum += p;
    }
#pragma unroll
    for (int off = 1; off < 16; off <<= 1) sum += __shfl_xor(sum, off, 16);
    float inv = 1.f / sum;
#pragma unroll
    for (int i = 0; i < 64; ++i) Ss[qr][tg + 16 * i] *= inv;
    __syncthreads();

    // write attn tile (16 x 1024), coalesced
    {
        float* ap = attn + ((size_t)bh * SEQ + qt * 16) * SEQ;
#pragma unroll
        for (int r = 0; r < 16; ++r) {
            int c = tid << 2;
            *(float4*)(ap + (size_t)r * SEQ + c) = *(const float4*)&Ss[r][c];
        }
    }

    // PV: ctx(16x64) = P(16x1024) V(1024x64), V streamed in 64-row tiles
    float4 acc = make_float4(0.f, 0.f, 0.f, 0.f);
    const int d0 = tg << 2;
    for (int vt = 0; vt < 16; ++vt) {
        __syncthreads();
#pragma unroll
        for (int i = 0; i < 4; ++i) {
            int idx = tid + (i << 8);
            int r   = idx >> 4;
            int c   = (idx & 15) << 2;
            *(float4*)&KVs[r][c] =
                *(const float4*)(vws + ((size_t)bh * SEQ + vt * 64 + r) * HD + c);
        }
        __syncthreads();
#pragma unroll
        for (int kk = 0; kk < 64; ++kk) {
            float p = Ss[qr][vt * 64 + kk];
            float4 vv = *(const float4*)&KVs[kk][d0];
            acc.x = fmaf(p, vv.x, acc.x);
            acc.y = fmaf(p, vv.y, acc.y);
            acc.z = fmaf(p, vv.z, acc.z);
            acc.w = fmaf(p, vv.w, acc.w);
        }
    }
    {
        int b = bh >> 4, h = bh & 15;
        int q = qt * 16 + qr;
        *(float4*)(ctx + (size_t)(b * SEQ + q) * EMB + h * HD + d0) = acc;
    }
}

extern "C" void kernel_launch(void* const* d_in, const int* in_sizes, int n_in,
                              void* d_out, int out_size, void* d_ws, size_t ws_size,
                              hipStream_t stream) {
    const float* x  = (const float*)d_in[0];
    const float* wq = (const float*)d_in[1];
    const float* bq = (const float*)d_in[2];
    const float* wk = (const float*)d_in[3];
    const float* bk = (const float*)d_in[4];
    const float* wv = (const float*)d_in[5];
    const float* bv = (const float*)d_in[6];
    const float* wo = (const float*)d_in[7];
    const float* bo = (const float*)d_in[8];

    float* out      = (float*)d_out;                         // (4,1024,1024)
    float* attn_out = out + (size_t)BATCH * SEQ * EMB;       // (4,16,1024,1024)

    const size_t qkv_elems = (size_t)BATCH * HEADS * SEQ * HD; // 4,194,304
    float* qws   = (float*)d_ws;
    float* kws   = qws + qkv_elems;
    float* vws   = kws + qkv_elems;
    float* ctxws = vws + qkv_elems;                          // 4096 x 1024 merged

    // 1) QKV projections
    qkv_kernel<<<dim3(EMB / GBN, MTOT / GBM, 3), 256, 0, stream>>>(
        x, wq, bq, wk, bk, wv, bv, qws, kws, vws);

    // 2) attention (scores + softmax + attn write + PV)
    attn_kernel<<<dim3(BATCH * HEADS, SEQ / 16), 256, 0, stream>>>(
        qws, kws, vws, attn_out, ctxws);

    // 3) output projection
    oproj_kernel<<<dim3(EMB / GBN, MTOT / GBM), 256, 0, stream>>>(
        ctxws, wo, bo, out);
}

// Round 2
// 1145.871 us; speedup vs baseline: 1.2593x; 1.2593x over previous
//
#include <hip/hip_runtime.h>
#include <math.h>

#define BATCH 4
#define SEQ   1024
#define EMB   1024
#define HEADS 16
#define HD    64
#define MTOT  (BATCH*SEQ)   // 4096

// ---------------- fp32 GEMM core: C = A @ W^T (+bias in epilogue) ----------
#define GBM 128
#define GBN 128
#define GBK 16

__device__ __forceinline__ void gemm_tile(const float* __restrict__ A,
                                          const float* __restrict__ W,
                                          int K, int m0, int n0,
                                          float acc[8][8])
{
    __shared__ float As[GBK][GBM + 4];
    __shared__ float Bs[GBK][GBN + 4];
    const int tid = threadIdx.x;
#pragma unroll
    for (int i = 0; i < 8; ++i)
#pragma unroll
        for (int j = 0; j < 8; ++j) acc[i][j] = 0.f;

    const int nk = K / GBK;
    for (int kt = 0; kt < nk; ++kt) {
        __syncthreads();
#pragma unroll
        for (int i = 0; i < 2; ++i) {
            int idx = (tid << 1) + i;
            int r   = idx >> 2;
            int c   = (idx & 3) << 2;
            float4 va = *(const float4*)(A + (size_t)(m0 + r) * K + kt * GBK + c);
            As[c + 0][r] = va.x; As[c + 1][r] = va.y;
            As[c + 2][r] = va.z; As[c + 3][r] = va.w;
            float4 vb = *(const float4*)(W + (size_t)(n0 + r) * K + kt * GBK + c);
            Bs[c + 0][r] = vb.x; Bs[c + 1][r] = vb.y;
            Bs[c + 2][r] = vb.z; Bs[c + 3][r] = vb.w;
        }
        __syncthreads();
        const int tx = tid & 15, ty = tid >> 4;
#pragma unroll
        for (int kk = 0; kk < GBK; ++kk) {
            float4 a0 = *(const float4*)&As[kk][ty * 8];
            float4 a1 = *(const float4*)&As[kk][ty * 8 + 4];
            float4 b0 = *(const float4*)&Bs[kk][tx * 8];
            float4 b1 = *(const float4*)&Bs[kk][tx * 8 + 4];
            float av[8] = {a0.x, a0.y, a0.z, a0.w, a1.x, a1.y, a1.z, a1.w};
            float bv[8] = {b0.x, b0.y, b0.z, b0.w, b1.x, b1.y, b1.z, b1.w};
#pragma unroll
            for (int i = 0; i < 8; ++i)
#pragma unroll
                for (int j = 0; j < 8; ++j)
                    acc[i][j] = fmaf(av[i], bv[j], acc[i][j]);
        }
    }
}

__global__ __launch_bounds__(256) void qkv_kernel(
    const float* __restrict__ x,
    const float* __restrict__ wq, const float* __restrict__ bq,
    const float* __restrict__ wk, const float* __restrict__ bk,
    const float* __restrict__ wv, const float* __restrict__ bv,
    float* __restrict__ qo, float* __restrict__ ko, float* __restrict__ vo)
{
    const float* Wm; const float* bias; float* outp;
    const int z = blockIdx.z;
    if (z == 0)      { Wm = wq; bias = bq; outp = qo; }
    else if (z == 1) { Wm = wk; bias = bk; outp = ko; }
    else             { Wm = wv; bias = bv; outp = vo; }
    const int m0 = blockIdx.y * GBM;
    const int n0 = blockIdx.x * GBN;
    float acc[8][8];
    gemm_tile(x, Wm, EMB, m0, n0, acc);
    const int tx = threadIdx.x & 15, ty = threadIdx.x >> 4;
#pragma unroll
    for (int i = 0; i < 8; ++i) {
        int m = m0 + ty * 8 + i;
        int b = m >> 10, s = m & (SEQ - 1);
#pragma unroll
        for (int j0 = 0; j0 < 8; j0 += 4) {
            int n = n0 + tx * 8 + j0;
            int h = n >> 6, d = n & 63;
            float4 v;
            v.x = acc[i][j0 + 0] + bias[n + 0];
            v.y = acc[i][j0 + 1] + bias[n + 1];
            v.z = acc[i][j0 + 2] + bias[n + 2];
            v.w = acc[i][j0 + 3] + bias[n + 3];
            *(float4*)(outp + ((size_t)(b * HEADS + h) * SEQ + s) * HD + d) = v;
        }
    }
}

__global__ __launch_bounds__(256) void oproj_kernel(
    const float* __restrict__ ctx, const float* __restrict__ wo,
    const float* __restrict__ bo, float* __restrict__ out)
{
    const int m0 = blockIdx.y * GBM;
    const int n0 = blockIdx.x * GBN;
    float acc[8][8];
    gemm_tile(ctx, wo, EMB, m0, n0, acc);
    const int tx = threadIdx.x & 15, ty = threadIdx.x >> 4;
#pragma unroll
    for (int i = 0; i < 8; ++i) {
        int m = m0 + ty * 8 + i;
#pragma unroll
        for (int j0 = 0; j0 < 8; j0 += 4) {
            int n = n0 + tx * 8 + j0;
            float4 v;
            v.x = acc[i][j0 + 0] + bo[n + 0];
            v.y = acc[i][j0 + 1] + bo[n + 1];
            v.z = acc[i][j0 + 2] + bo[n + 2];
            v.w = acc[i][j0 + 3] + bo[n + 3];
            *(float4*)(out + (size_t)m * EMB + n) = v;
        }
    }
}

// ---------------- attention, restructured ----------------------------------
// One block per (bh, 16-row q-tile). Scores live in registers (wave w owns
// rows 4w..4w+3; lane cl owns cols cl+64*kt). Softmax = in-register +
// wave-wide shfl_xor. P transposed through LDS in 4 chunks of 256 cols for
// the coalesced attn write + PV. XCD-aware swizzle groups all 64 q-tiles of
// a head on one XCD so K/V is HBM-fetched once per head.
__global__ __launch_bounds__(256, 4) void attn_kernel(
    const float* __restrict__ qws, const float* __restrict__ kws,
    const float* __restrict__ vws,
    float* __restrict__ attn, float* __restrict__ ctx)
{
    __shared__ float Qs[16][68];     // 4.3 KB
    __shared__ float Ks[64][68];     // 17.4 KB (K tile, reused for V)
    __shared__ float Ps[16][264];    // 16.9 KB (P transpose chunk)

    // swizzle: lid%8 = XCD slot; each XCD gets 8 whole heads (64 qt each)
    const int lid = blockIdx.y * gridDim.x + blockIdx.x;  // 0..4095
    const int xs  = lid & 7;
    const int j   = lid >> 3;          // 0..511
    const int bh  = xs * 8 + (j >> 6); // 0..63
    const int qt  = j & 63;            // 0..63

    const int tid = threadIdx.x;
    const int w   = tid >> 6;          // wave 0..3
    const int cl  = tid & 63;          // lane
    const int qr  = tid >> 4;          // 0..15 (staging / PV row)
    const int tg  = tid & 15;          // 0..15 (PV d-group)

    const float* Qg = qws + ((size_t)bh * SEQ + qt * 16) * HD;
    const float* Kg = kws + (size_t)bh * SEQ * HD;
    const float* Vg = vws + (size_t)bh * SEQ * HD;

    // load Q tile (16 x 64): one float4 per thread
    {
        int c = tg << 2;
        *(float4*)&Qs[qr][c] = *(const float4*)(Qg + (size_t)qr * HD + c);
    }

    float s[4][16];
#pragma unroll
    for (int i = 0; i < 4; ++i)
#pragma unroll
        for (int kt = 0; kt < 16; ++kt) s[i][kt] = 0.f;

    // ---- QK^T: 16 K-tiles of 64 rows ----
    for (int kt = 0; kt < 16; ++kt) {
        __syncthreads();
#pragma unroll
        for (int i = 0; i < 4; ++i) {
            int idx = tid + (i << 8);
            int r   = idx >> 4;
            int c   = (idx & 15) << 2;
            *(float4*)&Ks[r][c] =
                *(const float4*)(Kg + ((size_t)(kt * 64 + r)) * HD + c);
        }
        __syncthreads();
#pragma unroll
        for (int kk = 0; kk < 16; ++kk) {
            float4 kv = *(const float4*)&Ks[cl][kk * 4];
#pragma unroll
            for (int i = 0; i < 4; ++i) {
                float4 q = *(const float4*)&Qs[w * 4 + i][kk * 4];
                s[i][kt] = fmaf(q.x, kv.x,
                           fmaf(q.y, kv.y,
                           fmaf(q.z, kv.z,
                           fmaf(q.w, kv.w, s[i][kt]))));
            }
        }
    }

    // ---- softmax (in registers; row r is wholly inside wave w) ----
    float mx[4], sm[4];
#pragma unroll
    for (int i = 0; i < 4; ++i) {
        mx[i] = -1e30f;
#pragma unroll
        for (int kt = 0; kt < 16; ++kt) {
            s[i][kt] *= 0.125f;
            mx[i] = fmaxf(mx[i], s[i][kt]);
        }
    }
#pragma unroll
    for (int off = 1; off < 64; off <<= 1)
#pragma unroll
        for (int i = 0; i < 4; ++i)
            mx[i] = fmaxf(mx[i], __shfl_xor(mx[i], off));
#pragma unroll
    for (int i = 0; i < 4; ++i) {
        sm[i] = 0.f;
#pragma unroll
        for (int kt = 0; kt < 16; ++kt) {
            s[i][kt] = __expf(s[i][kt] - mx[i]);
            sm[i] += s[i][kt];
        }
    }
#pragma unroll
    for (int off = 1; off < 64; off <<= 1)
#pragma unroll
        for (int i = 0; i < 4; ++i)
            sm[i] += __shfl_xor(sm[i], off);
#pragma unroll
    for (int i = 0; i < 4; ++i) {
        float inv = 1.f / sm[i];
#pragma unroll
        for (int kt = 0; kt < 16; ++kt) s[i][kt] *= inv;
    }

    // ---- attn write + PV, in 4 chunks of 256 columns ----
    float4 acc = make_float4(0.f, 0.f, 0.f, 0.f);
    const int d0 = tg << 2;
    float* ap = attn + ((size_t)bh * SEQ + qt * 16) * SEQ;

    for (int ct = 0; ct < 4; ++ct) {
        __syncthreads();   // previous chunk's Ps reads done
#pragma unroll
        for (int i = 0; i < 4; ++i)
#pragma unroll
            for (int jj = 0; jj < 4; ++jj)
                Ps[w * 4 + i][jj * 64 + cl] = s[i][ct * 4 + jj];
        __syncthreads();
        // coalesced attn chunk write (16 rows x 256 cols)
#pragma unroll
        for (int pp = 0; pp < 4; ++pp) {
            int idx = tid + (pp << 8);          // 0..1023 f4 slots
            int r   = idx >> 6;
            int c4  = (idx & 63) << 2;
            *(float4*)(ap + (size_t)r * SEQ + ct * 256 + c4) =
                *(const float4*)&Ps[r][c4];
        }
        // PV over the chunk's 256 V rows (4 sub-tiles of 64)
        for (int vtl = 0; vtl < 4; ++vtl) {
            __syncthreads();   // prev tile reads done (Ks reused)
#pragma unroll
            for (int i = 0; i < 4; ++i) {
                int idx = tid + (i << 8);
                int r   = idx >> 4;
                int c   = (idx & 15) << 2;
                *(float4*)&Ks[r][c] =
                    *(const float4*)(Vg + ((size_t)((ct * 4 + vtl) * 64 + r)) * HD + c);
            }
            __syncthreads();
#pragma unroll
            for (int kk = 0; kk < 64; ++kk) {
                float  p  = Ps[qr][vtl * 64 + kk];
                float4 vv = *(const float4*)&Ks[kk][d0];
                acc.x = fmaf(p, vv.x, acc.x);
                acc.y = fmaf(p, vv.y, acc.y);
                acc.z = fmaf(p, vv.z, acc.z);
                acc.w = fmaf(p, vv.w, acc.w);
            }
        }
    }

    // ctx in merged (b, s, h*d) layout
    {
        int b = bh >> 4, h = bh & 15;
        int q = qt * 16 + qr;
        *(float4*)(ctx + ((size_t)(b * SEQ + q)) * EMB + h * HD + d0) = acc;
    }
}

extern "C" void kernel_launch(void* const* d_in, const int* in_sizes, int n_in,
                              void* d_out, int out_size, void* d_ws, size_t ws_size,
                              hipStream_t stream) {
    const float* x  = (const float*)d_in[0];
    const float* wq = (const float*)d_in[1];
    const float* bq = (const float*)d_in[2];
    const float* wk = (const float*)d_in[3];
    const float* bk = (const float*)d_in[4];
    const float* wv = (const float*)d_in[5];
    const float* bv = (const float*)d_in[6];
    const float* wo = (const float*)d_in[7];
    const float* bo = (const float*)d_in[8];

    float* out      = (float*)d_out;                         // (4,1024,1024)
    float* attn_out = out + (size_t)BATCH * SEQ * EMB;       // (4,16,1024,1024)

    const size_t qkv_elems = (size_t)BATCH * HEADS * SEQ * HD;
    float* qws   = (float*)d_ws;
    float* kws   = qws + qkv_elems;
    float* vws   = kws + qkv_elems;
    float* ctxws = vws + qkv_elems;

    qkv_kernel<<<dim3(EMB / GBN, MTOT / GBM, 3), 256, 0, stream>>>(
        x, wq, bq, wk, bk, wv, bv, qws, kws, vws);

    attn_kernel<<<dim3(SEQ / 16, BATCH * HEADS), 256, 0, stream>>>(
        qws, kws, vws, attn_out, ctxws);

    oproj_kernel<<<dim3(EMB / GBN, MTOT / GBM), 256, 0, stream>>>(
        ctxws, wo, bo, out);
}

// Round 4
// 865.082 us; speedup vs baseline: 1.6681x; 1.3246x over previous
//
#include <hip/hip_runtime.h>
#include <math.h>

#define BATCH 4
#define SEQ   1024
#define EMB   1024
#define HEADS 16
#define HD    64
#define MTOT  (BATCH*SEQ)   // 4096

typedef float vf4 __attribute__((ext_vector_type(4)));

// ---------------- fp32 GEMM core: C = A @ W^T (+bias in epilogue) ----------
#define GBM 128
#define GBN 128
#define GBK 16

__device__ __forceinline__ void gemm_tile(const float* __restrict__ A,
                                          const float* __restrict__ W,
                                          int K, int m0, int n0,
                                          float acc[8][8])
{
    __shared__ float As[GBK][GBM + 4];
    __shared__ float Bs[GBK][GBN + 4];
    const int tid = threadIdx.x;
#pragma unroll
    for (int i = 0; i < 8; ++i)
#pragma unroll
        for (int j = 0; j < 8; ++j) acc[i][j] = 0.f;

    const int nk = K / GBK;
    for (int kt = 0; kt < nk; ++kt) {
        __syncthreads();
#pragma unroll
        for (int i = 0; i < 2; ++i) {
            int idx = (tid << 1) + i;
            int r   = idx >> 2;
            int c   = (idx & 3) << 2;
            float4 va = *(const float4*)(A + (size_t)(m0 + r) * K + kt * GBK + c);
            As[c + 0][r] = va.x; As[c + 1][r] = va.y;
            As[c + 2][r] = va.z; As[c + 3][r] = va.w;
            float4 vb = *(const float4*)(W + (size_t)(n0 + r) * K + kt * GBK + c);
            Bs[c + 0][r] = vb.x; Bs[c + 1][r] = vb.y;
            Bs[c + 2][r] = vb.z; Bs[c + 3][r] = vb.w;
        }
        __syncthreads();
        const int tx = tid & 15, ty = tid >> 4;
#pragma unroll
        for (int kk = 0; kk < GBK; ++kk) {
            float4 a0 = *(const float4*)&As[kk][ty * 8];
            float4 a1 = *(const float4*)&As[kk][ty * 8 + 4];
            float4 b0 = *(const float4*)&Bs[kk][tx * 8];
            float4 b1 = *(const float4*)&Bs[kk][tx * 8 + 4];
            float av[8] = {a0.x, a0.y, a0.z, a0.w, a1.x, a1.y, a1.z, a1.w};
            float bv[8] = {b0.x, b0.y, b0.z, b0.w, b1.x, b1.y, b1.z, b1.w};
#pragma unroll
            for (int i = 0; i < 8; ++i)
#pragma unroll
                for (int j = 0; j < 8; ++j)
                    acc[i][j] = fmaf(av[i], bv[j], acc[i][j]);
        }
    }
}

__global__ __launch_bounds__(256) void qkv_kernel(
    const float* __restrict__ x,
    const float* __restrict__ wq, const float* __restrict__ bq,
    const float* __restrict__ wk, const float* __restrict__ bk,
    const float* __restrict__ wv, const float* __restrict__ bv,
    float* __restrict__ qo, float* __restrict__ ko, float* __restrict__ vo)
{
    const float* Wm; const float* bias; float* outp;
    const int z = blockIdx.z;
    if (z == 0)      { Wm = wq; bias = bq; outp = qo; }
    else if (z == 1) { Wm = wk; bias = bk; outp = ko; }
    else             { Wm = wv; bias = bv; outp = vo; }
    const int m0 = blockIdx.y * GBM;
    const int n0 = blockIdx.x * GBN;
    float acc[8][8];
    gemm_tile(x, Wm, EMB, m0, n0, acc);
    const int tx = threadIdx.x & 15, ty = threadIdx.x >> 4;
#pragma unroll
    for (int i = 0; i < 8; ++i) {
        int m = m0 + ty * 8 + i;
        int b = m >> 10, s = m & (SEQ - 1);
#pragma unroll
        for (int j0 = 0; j0 < 8; j0 += 4) {
            int n = n0 + tx * 8 + j0;
            int h = n >> 6, d = n & 63;
            float4 v;
            v.x = acc[i][j0 + 0] + bias[n + 0];
            v.y = acc[i][j0 + 1] + bias[n + 1];
            v.z = acc[i][j0 + 2] + bias[n + 2];
            v.w = acc[i][j0 + 3] + bias[n + 3];
            *(float4*)(outp + ((size_t)(b * HEADS + h) * SEQ + s) * HD + d) = v;
        }
    }
}

__global__ __launch_bounds__(256) void oproj_kernel(
    const float* __restrict__ ctx, const float* __restrict__ wo,
    const float* __restrict__ bo, float* __restrict__ out)
{
    const int m0 = blockIdx.y * GBM;
    const int n0 = blockIdx.x * GBN;
    float acc[8][8];
    gemm_tile(ctx, wo, EMB, m0, n0, acc);
    const int tx = threadIdx.x & 15, ty = threadIdx.x >> 4;
#pragma unroll
    for (int i = 0; i < 8; ++i) {
        int m = m0 + ty * 8 + i;
#pragma unroll
        for (int j0 = 0; j0 < 8; j0 += 4) {
            int n = n0 + tx * 8 + j0;
            float4 v;
            v.x = acc[i][j0 + 0] + bo[n + 0];
            v.y = acc[i][j0 + 1] + bo[n + 1];
            v.z = acc[i][j0 + 2] + bo[n + 2];
            v.w = acc[i][j0 + 3] + bo[n + 3];
            *(float4*)(out + (size_t)m * EMB + n) = v;
        }
    }
}

// ---------------- attention ------------------------------------------------
// One block per (bh, 16-row q-tile). Scores in REGISTERS with all indexing
// compile-time (kt/ct loops fully unrolled — runtime-indexed arrays would be
// demoted to scratch, which round 2 measured as 1.35 GB of HBM writes).
// Softmax = in-register + wave shfl_xor. P transposed through LDS in 4
// chunks of 256 cols for the coalesced attn write (nontemporal) + PV.
__global__ __launch_bounds__(256, 4) void attn_kernel(
    const float* __restrict__ qws, const float* __restrict__ kws,
    const float* __restrict__ vws,
    float* __restrict__ attn, float* __restrict__ ctx)
{
    __shared__ float Qs[16][68];     // 4.3 KB
    __shared__ float Ks[64][68];     // 17.4 KB (K tile, reused for V)
    __shared__ float Ps[16][264];    // 16.9 KB (P transpose chunk)

    // swizzle: all 64 q-tiles of a head land on one XCD (round-robin lid%8)
    const int lid = blockIdx.y * gridDim.x + blockIdx.x;  // 0..4095
    const int xs  = lid & 7;
    const int j   = lid >> 3;          // 0..511
    const int bh  = xs * 8 + (j >> 6); // 0..63
    const int qt  = j & 63;            // 0..63

    const int tid = threadIdx.x;
    const int w   = tid >> 6;          // wave 0..3
    const int cl  = tid & 63;          // lane
    const int qr  = tid >> 4;          // 0..15 (staging / PV row)
    const int tg  = tid & 15;          // 0..15 (PV d-group)

    const float* Qg = qws + ((size_t)bh * SEQ + qt * 16) * HD;
    const float* Kg = kws + (size_t)bh * SEQ * HD;
    const float* Vg = vws + (size_t)bh * SEQ * HD;

    {
        int c = tg << 2;
        *(float4*)&Qs[qr][c] = *(const float4*)(Qg + (size_t)qr * HD + c);
    }

    float s[4][16];
#pragma unroll
    for (int i = 0; i < 4; ++i)
#pragma unroll
        for (int kt = 0; kt < 16; ++kt) s[i][kt] = 0.f;

    // ---- QK^T: 16 K-tiles of 64 rows; kt FULLY UNROLLED (static s index) --
#pragma unroll
    for (int kt = 0; kt < 16; ++kt) {
        __syncthreads();
#pragma unroll
        for (int i = 0; i < 4; ++i) {
            int idx = tid + (i << 8);
            int r   = idx >> 4;
            int c   = (idx & 15) << 2;
            *(float4*)&Ks[r][c] =
                *(const float4*)(Kg + ((size_t)(kt * 64 + r)) * HD + c);
        }
        __syncthreads();
#pragma unroll
        for (int kk = 0; kk < 16; ++kk) {
            float4 kv = *(const float4*)&Ks[cl][kk * 4];
#pragma unroll
            for (int i = 0; i < 4; ++i) {
                float4 q = *(const float4*)&Qs[w * 4 + i][kk * 4];
                s[i][kt] = fmaf(q.x, kv.x,
                           fmaf(q.y, kv.y,
                           fmaf(q.z, kv.z,
                           fmaf(q.w, kv.w, s[i][kt]))));
            }
        }
    }

    // ---- softmax (in registers; row r wholly inside wave w) ----
    float mx[4], sm[4];
#pragma unroll
    for (int i = 0; i < 4; ++i) {
        mx[i] = -1e30f;
#pragma unroll
        for (int kt = 0; kt < 16; ++kt) {
            s[i][kt] *= 0.125f;
            mx[i] = fmaxf(mx[i], s[i][kt]);
        }
    }
#pragma unroll
    for (int off = 1; off < 64; off <<= 1)
#pragma unroll
        for (int i = 0; i < 4; ++i)
            mx[i] = fmaxf(mx[i], __shfl_xor(mx[i], off));
#pragma unroll
    for (int i = 0; i < 4; ++i) {
        sm[i] = 0.f;
#pragma unroll
        for (int kt = 0; kt < 16; ++kt) {
            s[i][kt] = __expf(s[i][kt] - mx[i]);
            sm[i] += s[i][kt];
        }
    }
#pragma unroll
    for (int off = 1; off < 64; off <<= 1)
#pragma unroll
        for (int i = 0; i < 4; ++i)
            sm[i] += __shfl_xor(sm[i], off);
#pragma unroll
    for (int i = 0; i < 4; ++i) {
        float inv = 1.f / sm[i];
#pragma unroll
        for (int kt = 0; kt < 16; ++kt) s[i][kt] *= inv;
    }

    // ---- attn write + PV, 4 chunks of 256 cols; ct FULLY UNROLLED ----
    float4 acc = make_float4(0.f, 0.f, 0.f, 0.f);
    const int d0 = tg << 2;
    float* ap = attn + ((size_t)bh * SEQ + qt * 16) * SEQ;

#pragma unroll
    for (int ct = 0; ct < 4; ++ct) {
        __syncthreads();   // previous chunk's Ps reads done
#pragma unroll
        for (int i = 0; i < 4; ++i)
#pragma unroll
            for (int jj = 0; jj < 4; ++jj)
                Ps[w * 4 + i][jj * 64 + cl] = s[i][ct * 4 + jj];
        __syncthreads();
        // coalesced attn chunk write (16 rows x 256 cols), nontemporal
#pragma unroll
        for (int pp = 0; pp < 4; ++pp) {
            int idx = tid + (pp << 8);
            int r   = idx >> 6;
            int c4  = (idx & 63) << 2;
            vf4 pv = *(const vf4*)&Ps[r][c4];
            __builtin_nontemporal_store(pv,
                (vf4*)(ap + (size_t)r * SEQ + ct * 256 + c4));
        }
        // PV over the chunk's 256 V rows (4 sub-tiles of 64)
        for (int vtl = 0; vtl < 4; ++vtl) {
            __syncthreads();   // prev tile reads done (Ks reused)
#pragma unroll
            for (int i = 0; i < 4; ++i) {
                int idx = tid + (i << 8);
                int r   = idx >> 4;
                int c   = (idx & 15) << 2;
                *(float4*)&Ks[r][c] =
                    *(const float4*)(Vg + ((size_t)((ct * 4 + vtl) * 64 + r)) * HD + c);
            }
            __syncthreads();
#pragma unroll
            for (int kk = 0; kk < 64; ++kk) {
                float  p  = Ps[qr][vtl * 64 + kk];
                float4 vv = *(const float4*)&Ks[kk][d0];
                acc.x = fmaf(p, vv.x, acc.x);
                acc.y = fmaf(p, vv.y, acc.y);
                acc.z = fmaf(p, vv.z, acc.z);
                acc.w = fmaf(p, vv.w, acc.w);
            }
        }
    }

    {
        int b = bh >> 4, h = bh & 15;
        int q = qt * 16 + qr;
        *(float4*)(ctx + ((size_t)(b * SEQ + q)) * EMB + h * HD + d0) = acc;
    }
}

extern "C" void kernel_launch(void* const* d_in, const int* in_sizes, int n_in,
                              void* d_out, int out_size, void* d_ws, size_t ws_size,
                              hipStream_t stream) {
    const float* x  = (const float*)d_in[0];
    const float* wq = (const float*)d_in[1];
    const float* bq = (const float*)d_in[2];
    const float* wk = (const float*)d_in[3];
    const float* bk = (const float*)d_in[4];
    const float* wv = (const float*)d_in[5];
    const float* bv = (const float*)d_in[6];
    const float* wo = (const float*)d_in[7];
    const float* bo = (const float*)d_in[8];

    float* out      = (float*)d_out;                         // (4,1024,1024)
    float* attn_out = out + (size_t)BATCH * SEQ * EMB;       // (4,16,1024,1024)

    const size_t qkv_elems = (size_t)BATCH * HEADS * SEQ * HD;
    float* qws   = (float*)d_ws;
    float* kws   = qws + qkv_elems;
    float* vws   = kws + qkv_elems;
    float* ctxws = vws + qkv_elems;

    qkv_kernel<<<dim3(EMB / GBN, MTOT / GBM, 3), 256, 0, stream>>>(
        x, wq, bq, wk, bk, wv, bv, qws, kws, vws);

    attn_kernel<<<dim3(SEQ / 16, BATCH * HEADS), 256, 0, stream>>>(
        qws, kws, vws, attn_out, ctxws);

    oproj_kernel<<<dim3(EMB / GBN, MTOT / GBM), 256, 0, stream>>>(
        ctxws, wo, bo, out);
}

// Round 5
// 542.378 us; speedup vs baseline: 2.6606x; 1.5950x over previous
//
#include <hip/hip_runtime.h>
#include <math.h>

#define BATCH 4
#define SEQ   1024
#define EMB   1024
#define HEADS 16
#define HD    64
#define MTOT  (BATCH*SEQ)   // 4096

typedef float vf4   __attribute__((ext_vector_type(4)));
typedef float f32x4 __attribute__((ext_vector_type(4)));
typedef short s16x8 __attribute__((ext_vector_type(8)));

// ---- bf16 hi/lo split helpers (RNE) ---------------------------------------
__device__ __forceinline__ unsigned short f2bf(float f) {
    unsigned u = __float_as_uint(f);
    unsigned r = u + 0x7fffu + ((u >> 16) & 1u);
    return (unsigned short)(r >> 16);
}
__device__ __forceinline__ float bf2f(unsigned short h) {
    return __uint_as_float(((unsigned)h) << 16);
}

// ---- conversion kernels ---------------------------------------------------
// one block per 1024-elem row; 256 thr x 4 elems
__global__ __launch_bounds__(256) void convert_x(
    const float* __restrict__ in, unsigned short* __restrict__ hi,
    unsigned short* __restrict__ lo)
{
    size_t base = ((size_t)blockIdx.x << 10) + (threadIdx.x << 2);
    float4 v = *(const float4*)(in + base);
    ushort4 h, l;
    h.x = f2bf(v.x); l.x = f2bf(v.x - bf2f(h.x));
    h.y = f2bf(v.y); l.y = f2bf(v.y - bf2f(h.y));
    h.z = f2bf(v.z); l.z = f2bf(v.z - bf2f(h.z));
    h.w = f2bf(v.w); l.w = f2bf(v.w - bf2f(h.w));
    *(ushort4*)(hi + base) = h;
    *(ushort4*)(lo + base) = l;
}

// 4 weight matrices -> planes 0..3 of whi/wlo
__global__ __launch_bounds__(256) void convert_w4(
    const float* __restrict__ wq, const float* __restrict__ wk,
    const float* __restrict__ wv, const float* __restrict__ wo,
    unsigned short* __restrict__ hi, unsigned short* __restrict__ lo)
{
    int mi = blockIdx.x >> 10;
    int r  = blockIdx.x & 1023;
    const float* in = (mi == 0) ? wq : (mi == 1) ? wk : (mi == 2) ? wv : wo;
    size_t ib = ((size_t)r << 10) + (threadIdx.x << 2);
    size_t ob = ((size_t)mi << 20) + ib;
    float4 v = *(const float4*)(in + ib);
    ushort4 h, l;
    h.x = f2bf(v.x); l.x = f2bf(v.x - bf2f(h.x));
    h.y = f2bf(v.y); l.y = f2bf(v.y - bf2f(h.y));
    h.z = f2bf(v.z); l.z = f2bf(v.z - bf2f(h.z));
    h.w = f2bf(v.w); l.w = f2bf(v.w - bf2f(h.w));
    *(ushort4*)(hi + ob) = h;
    *(ushort4*)(lo + ob) = l;
}

// ---- split-bf16 MFMA GEMM tile --------------------------------------------
// C(128x128) = A_f32 @ W_f32^T done as 3 bf16 passes over K'=3*1024:
//   seg0: Ahi*Whi, seg1: Ahi*Wlo, seg2: Alo*Whi  (fp32 MFMA accumulate)
// 4 waves (2x2), wave tile 64x64 = 4x4 frags of 16x16, BK=64.
#define BM  128
#define BN  128
#define BKS 64
#define LDT 72   // padded LDS row stride (ushorts): 2-way banks = free

__device__ __forceinline__ void mfma_gemm_tile(
    const unsigned short* __restrict__ Ahi, const unsigned short* __restrict__ Alo,
    const unsigned short* __restrict__ Bhi, const unsigned short* __restrict__ Blo,
    int m0, int n0, f32x4 acc[4][4])
{
    __shared__ unsigned short As[BM * LDT];
    __shared__ unsigned short Bs[BM * LDT];
    const int tid  = threadIdx.x;
    const int lane = tid & 63;
    const int w    = tid >> 6;
    const int wr   = w >> 1, wc = w & 1;
    const int fr   = lane & 15;
    const int kb   = lane >> 4;

#pragma unroll
    for (int i = 0; i < 4; ++i)
#pragma unroll
        for (int j = 0; j < 4; ++j) acc[i][j] = (f32x4){0.f, 0.f, 0.f, 0.f};

    s16x8 ra[4], rb[4];
    // chunk c = tid + i*256 (0..1023): row=c>>3, 16B col chunk cc=c&7
#define LOAD_STEP(KT)                                                          \
    {                                                                          \
        int seg = (KT) >> 4;                                                   \
        int k0  = ((KT) & 15) * BKS;                                           \
        const unsigned short* Ap = (seg < 2) ? Ahi : Alo;                      \
        const unsigned short* Bp = (seg == 1) ? Blo : Bhi;                     \
        _Pragma("unroll")                                                      \
        for (int i = 0; i < 4; ++i) {                                          \
            int c = tid + (i << 8);                                            \
            int row = c >> 3, cc = (c & 7) << 3;                               \
            ra[i] = *(const s16x8*)(Ap + ((size_t)(m0 + row) << 10) + k0 + cc);\
            rb[i] = *(const s16x8*)(Bp + ((size_t)(n0 + row) << 10) + k0 + cc);\
        }                                                                      \
    }

    LOAD_STEP(0);
    for (int kt = 0; kt < 48; ++kt) {
        __syncthreads();          // prev frag reads done
#pragma unroll
        for (int i = 0; i < 4; ++i) {
            int c = tid + (i << 8);
            int row = c >> 3, cc = (c & 7) << 3;
            *(s16x8*)&As[row * LDT + cc] = ra[i];
            *(s16x8*)&Bs[row * LDT + cc] = rb[i];
        }
        if (kt + 1 < 48) LOAD_STEP(kt + 1);   // issue next tile early
        __syncthreads();
#pragma unroll
        for (int kc = 0; kc < 2; ++kc) {
            s16x8 aF[4], bF[4];
#pragma unroll
            for (int i = 0; i < 4; ++i)
                aF[i] = *(const s16x8*)&As[(wr * 64 + i * 16 + fr) * LDT + kc * 32 + kb * 8];
#pragma unroll
            for (int j = 0; j < 4; ++j)
                bF[j] = *(const s16x8*)&Bs[(wc * 64 + j * 16 + fr) * LDT + kc * 32 + kb * 8];
#pragma unroll
            for (int i = 0; i < 4; ++i)
#pragma unroll
                for (int j = 0; j < 4; ++j)
                    acc[i][j] = __builtin_amdgcn_mfma_f32_16x16x32_bf16(
                        aF[i], bF[j], acc[i][j], 0, 0, 0);
        }
    }
#undef LOAD_STEP
}

// QKV: z selects weight plane; writes Q/K/V fp32 in (b,h,s,d) layout
__global__ __launch_bounds__(256, 2) void qkv_mfma(
    const unsigned short* __restrict__ xhi, const unsigned short* __restrict__ xlo,
    const unsigned short* __restrict__ whi, const unsigned short* __restrict__ wlo,
    const float* __restrict__ bq, const float* __restrict__ bk,
    const float* __restrict__ bv,
    float* __restrict__ qo, float* __restrict__ ko, float* __restrict__ vo)
{
    const int z = blockIdx.z;
    const unsigned short* Bh = whi + ((size_t)z << 20);
    const unsigned short* Bl = wlo + ((size_t)z << 20);
    const float* bias = (z == 0) ? bq : (z == 1) ? bk : bv;
    float* outp       = (z == 0) ? qo : (z == 1) ? ko : vo;
    const int m0 = blockIdx.y * BM, n0 = blockIdx.x * BN;
    f32x4 acc[4][4];
    mfma_gemm_tile(xhi, xlo, Bh, Bl, m0, n0, acc);

    const int lane = threadIdx.x & 63;
    const int w    = threadIdx.x >> 6;
    const int wr   = w >> 1, wc = w & 1;
    const int fr   = lane & 15;   // col within frag
    const int rg   = lane >> 4;   // row group
#pragma unroll
    for (int i = 0; i < 4; ++i)
#pragma unroll
        for (int j = 0; j < 4; ++j) {
            int n = n0 + wc * 64 + j * 16 + fr;
            int h = n >> 6, d = n & 63;
            float bv_ = bias[n];
#pragma unroll
            for (int r = 0; r < 4; ++r) {
                int m = m0 + wr * 64 + i * 16 + rg * 4 + r;
                int b = m >> 10, s = m & 1023;
                outp[((size_t)(b * HEADS + h) * SEQ + s) * HD + d] =
                    acc[i][j][r] + bv_;
            }
        }
}

// OPROJ: ctx' (bf16 hi/lo) @ wo^T + bo -> out fp32
__global__ __launch_bounds__(256, 2) void oproj_mfma(
    const unsigned short* __restrict__ chi, const unsigned short* __restrict__ clo,
    const unsigned short* __restrict__ whi, const unsigned short* __restrict__ wlo,
    const float* __restrict__ bo, float* __restrict__ out)
{
    const unsigned short* Bh = whi + ((size_t)3 << 20);
    const unsigned short* Bl = wlo + ((size_t)3 << 20);
    const int m0 = blockIdx.y * BM, n0 = blockIdx.x * BN;
    f32x4 acc[4][4];
    mfma_gemm_tile(chi, clo, Bh, Bl, m0, n0, acc);

    const int lane = threadIdx.x & 63;
    const int w    = threadIdx.x >> 6;
    const int wr   = w >> 1, wc = w & 1;
    const int fr   = lane & 15;
    const int rg   = lane >> 4;
#pragma unroll
    for (int i = 0; i < 4; ++i)
#pragma unroll
        for (int j = 0; j < 4; ++j) {
            int n = n0 + wc * 64 + j * 16 + fr;
            float bv_ = bo[n];
#pragma unroll
            for (int r = 0; r < 4; ++r) {
                int m = m0 + wr * 64 + i * 16 + rg * 4 + r;
                out[(size_t)m * EMB + n] = acc[i][j][r] + bv_;
            }
        }
}

// ---------------- attention (fp32, register scores) ------------------------
__global__ __launch_bounds__(256, 2) void attn_kernel(
    const float* __restrict__ qws, const float* __restrict__ kws,
    const float* __restrict__ vws,
    float* __restrict__ attn,
    unsigned short* __restrict__ chi, unsigned short* __restrict__ clo)
{
    __shared__ float Qs[16][68];
    __shared__ float Ks[64][68];
    __shared__ float Ps[16][264];

    const int lid = blockIdx.y * gridDim.x + blockIdx.x;
    const int xs  = lid & 7;
    const int j   = lid >> 3;
    const int bh  = xs * 8 + (j >> 6);
    const int qt  = j & 63;

    const int tid = threadIdx.x;
    const int w   = tid >> 6;
    const int cl  = tid & 63;
    const int qr  = tid >> 4;
    const int tg  = tid & 15;

    const float* Qg = qws + ((size_t)bh * SEQ + qt * 16) * HD;
    const float* Kg = kws + (size_t)bh * SEQ * HD;
    const float* Vg = vws + (size_t)bh * SEQ * HD;

    {
        int c = tg << 2;
        *(float4*)&Qs[qr][c] = *(const float4*)(Qg + (size_t)qr * HD + c);
    }

    float s[4][16];
#pragma unroll
    for (int i = 0; i < 4; ++i)
#pragma unroll
        for (int kt = 0; kt < 16; ++kt) s[i][kt] = 0.f;

#pragma unroll
    for (int kt = 0; kt < 16; ++kt) {
        __syncthreads();
#pragma unroll
        for (int i = 0; i < 4; ++i) {
            int idx = tid + (i << 8);
            int r   = idx >> 4;
            int c   = (idx & 15) << 2;
            *(float4*)&Ks[r][c] =
                *(const float4*)(Kg + ((size_t)(kt * 64 + r)) * HD + c);
        }
        __syncthreads();
#pragma unroll
        for (int kk = 0; kk < 16; ++kk) {
            float4 kv = *(const float4*)&Ks[cl][kk * 4];
#pragma unroll
            for (int i = 0; i < 4; ++i) {
                float4 q = *(const float4*)&Qs[w * 4 + i][kk * 4];
                s[i][kt] = fmaf(q.x, kv.x,
                           fmaf(q.y, kv.y,
                           fmaf(q.z, kv.z,
                           fmaf(q.w, kv.w, s[i][kt]))));
            }
        }
    }

    float mx[4], sm[4];
#pragma unroll
    for (int i = 0; i < 4; ++i) {
        mx[i] = -1e30f;
#pragma unroll
        for (int kt = 0; kt < 16; ++kt) {
            s[i][kt] *= 0.125f;
            mx[i] = fmaxf(mx[i], s[i][kt]);
        }
    }
#pragma unroll
    for (int off = 1; off < 64; off <<= 1)
#pragma unroll
        for (int i = 0; i < 4; ++i)
            mx[i] = fmaxf(mx[i], __shfl_xor(mx[i], off));
#pragma unroll
    for (int i = 0; i < 4; ++i) {
        sm[i] = 0.f;
#pragma unroll
        for (int kt = 0; kt < 16; ++kt) {
            s[i][kt] = __expf(s[i][kt] - mx[i]);
            sm[i] += s[i][kt];
        }
    }
#pragma unroll
    for (int off = 1; off < 64; off <<= 1)
#pragma unroll
        for (int i = 0; i < 4; ++i)
            sm[i] += __shfl_xor(sm[i], off);
#pragma unroll
    for (int i = 0; i < 4; ++i) {
        float inv = 1.f / sm[i];
#pragma unroll
        for (int kt = 0; kt < 16; ++kt) s[i][kt] *= inv;
    }

    float4 acc = make_float4(0.f, 0.f, 0.f, 0.f);
    const int d0 = tg << 2;
    float* ap = attn + ((size_t)bh * SEQ + qt * 16) * SEQ;

#pragma unroll
    for (int ct = 0; ct < 4; ++ct) {
        __syncthreads();
#pragma unroll
        for (int i = 0; i < 4; ++i)
#pragma unroll
            for (int jj = 0; jj < 4; ++jj)
                Ps[w * 4 + i][jj * 64 + cl] = s[i][ct * 4 + jj];
        __syncthreads();
#pragma unroll
        for (int pp = 0; pp < 4; ++pp) {
            int idx = tid + (pp << 8);
            int r   = idx >> 6;
            int c4  = (idx & 63) << 2;
            vf4 pv = *(const vf4*)&Ps[r][c4];
            __builtin_nontemporal_store(pv,
                (vf4*)(ap + (size_t)r * SEQ + ct * 256 + c4));
        }
        for (int vtl = 0; vtl < 4; ++vtl) {
            __syncthreads();
#pragma unroll
            for (int i = 0; i < 4; ++i) {
                int idx = tid + (i << 8);
                int r   = idx >> 4;
                int c   = (idx & 15) << 2;
                *(float4*)&Ks[r][c] =
                    *(const float4*)(Vg + ((size_t)((ct * 4 + vtl) * 64 + r)) * HD + c);
            }
            __syncthreads();
#pragma unroll
            for (int kk = 0; kk < 64; ++kk) {
                float  p  = Ps[qr][vtl * 64 + kk];
                float4 vv = *(const float4*)&Ks[kk][d0];
                acc.x = fmaf(p, vv.x, acc.x);
                acc.y = fmaf(p, vv.y, acc.y);
                acc.z = fmaf(p, vv.z, acc.z);
                acc.w = fmaf(p, vv.w, acc.w);
            }
        }
    }

    {
        int b = bh >> 4, h = bh & 15;
        int q = qt * 16 + qr;
        size_t base = ((size_t)(b * SEQ + q) << 10) + h * HD + d0;
        ushort4 h4, l4;
        h4.x = f2bf(acc.x); l4.x = f2bf(acc.x - bf2f(h4.x));
        h4.y = f2bf(acc.y); l4.y = f2bf(acc.y - bf2f(h4.y));
        h4.z = f2bf(acc.z); l4.z = f2bf(acc.z - bf2f(h4.z));
        h4.w = f2bf(acc.w); l4.w = f2bf(acc.w - bf2f(h4.w));
        *(ushort4*)(chi + base) = h4;
        *(ushort4*)(clo + base) = l4;
    }
}

extern "C" void kernel_launch(void* const* d_in, const int* in_sizes, int n_in,
                              void* d_out, int out_size, void* d_ws, size_t ws_size,
                              hipStream_t stream) {
    const float* x  = (const float*)d_in[0];
    const float* wq = (const float*)d_in[1];
    const float* bq = (const float*)d_in[2];
    const float* wk = (const float*)d_in[3];
    const float* bk = (const float*)d_in[4];
    const float* wv = (const float*)d_in[5];
    const float* bv = (const float*)d_in[6];
    const float* wo = (const float*)d_in[7];
    const float* bo = (const float*)d_in[8];

    float* out      = (float*)d_out;
    float* attn_out = out + (size_t)BATCH * SEQ * EMB;

    const size_t MK = (size_t)MTOT * 1024;   // 4,194,304
    unsigned short* ws16 = (unsigned short*)d_ws;
    unsigned short* xhi = ws16;
    unsigned short* xlo = xhi + MK;
    unsigned short* whi = xlo + MK;          // 4 planes of 1024x1024
    unsigned short* wlo = whi + MK;
    float* qws = (float*)(wlo + MK);
    float* kws = qws + MK;
    float* vws = kws + MK;
    unsigned short* chi = xhi;               // x' dead after qkv
    unsigned short* clo = xlo;

    convert_x<<<MTOT, 256, 0, stream>>>(x, xhi, xlo);
    convert_w4<<<4096, 256, 0, stream>>>(wq, wk, wv, wo, whi, wlo);

    qkv_mfma<<<dim3(EMB / BN, MTOT / BM, 3), 256, 0, stream>>>(
        xhi, xlo, whi, wlo, bq, bk, bv, qws, kws, vws);

    attn_kernel<<<dim3(SEQ / 16, BATCH * HEADS), 256, 0, stream>>>(
        qws, kws, vws, attn_out, chi, clo);

    oproj_mfma<<<dim3(EMB / BN, MTOT / BM), 256, 0, stream>>>(
        chi, clo, whi, wlo, bo, out);
}

// Round 6
// 300.975 us; speedup vs baseline: 4.7946x; 1.8021x over previous
//
#include <hip/hip_runtime.h>
#include <math.h>

#define BATCH 4
#define SEQ   1024
#define EMB   1024
#define HEADS 16
#define HD    64
#define MTOT  (BATCH*SEQ)   // 4096

typedef float f32x4 __attribute__((ext_vector_type(4)));
typedef short s16x8 __attribute__((ext_vector_type(8)));

// ---- bf16 hi/lo split helpers (RNE) ---------------------------------------
__device__ __forceinline__ unsigned short f2bf(float f) {
    unsigned u = __float_as_uint(f);
    unsigned r = u + 0x7fffu + ((u >> 16) & 1u);
    return (unsigned short)(r >> 16);
}
__device__ __forceinline__ float bf2f(unsigned short h) {
    return __uint_as_float(((unsigned)h) << 16);
}

// ---- conversion kernels ---------------------------------------------------
__global__ __launch_bounds__(256) void convert_x(
    const float* __restrict__ in, unsigned short* __restrict__ hi,
    unsigned short* __restrict__ lo)
{
    size_t base = ((size_t)blockIdx.x << 10) + (threadIdx.x << 2);
    float4 v = *(const float4*)(in + base);
    ushort4 h, l;
    h.x = f2bf(v.x); l.x = f2bf(v.x - bf2f(h.x));
    h.y = f2bf(v.y); l.y = f2bf(v.y - bf2f(h.y));
    h.z = f2bf(v.z); l.z = f2bf(v.z - bf2f(h.z));
    h.w = f2bf(v.w); l.w = f2bf(v.w - bf2f(h.w));
    *(ushort4*)(hi + base) = h;
    *(ushort4*)(lo + base) = l;
}

__global__ __launch_bounds__(256) void convert_w4(
    const float* __restrict__ wq, const float* __restrict__ wk,
    const float* __restrict__ wv, const float* __restrict__ wo,
    unsigned short* __restrict__ hi, unsigned short* __restrict__ lo)
{
    int mi = blockIdx.x >> 10;
    int r  = blockIdx.x & 1023;
    const float* in = (mi == 0) ? wq : (mi == 1) ? wk : (mi == 2) ? wv : wo;
    size_t ib = ((size_t)r << 10) + (threadIdx.x << 2);
    size_t ob = ((size_t)mi << 20) + ib;
    float4 v = *(const float4*)(in + ib);
    ushort4 h, l;
    h.x = f2bf(v.x); l.x = f2bf(v.x - bf2f(h.x));
    h.y = f2bf(v.y); l.y = f2bf(v.y - bf2f(h.y));
    h.z = f2bf(v.z); l.z = f2bf(v.z - bf2f(h.z));
    h.w = f2bf(v.w); l.w = f2bf(v.w - bf2f(h.w));
    *(ushort4*)(hi + ob) = h;
    *(ushort4*)(lo + ob) = l;
}

// ---- split-bf16 MFMA GEMM tile (unchanged from round 5) -------------------
#define BM  128
#define BN  128
#define BKS 64
#define LDT 72

__device__ __forceinline__ void mfma_gemm_tile(
    const unsigned short* __restrict__ Ahi, const unsigned short* __restrict__ Alo,
    const unsigned short* __restrict__ Bhi, const unsigned short* __restrict__ Blo,
    int m0, int n0, f32x4 acc[4][4])
{
    __shared__ unsigned short As[BM * LDT];
    __shared__ unsigned short Bs[BM * LDT];
    const int tid  = threadIdx.x;
    const int lane = tid & 63;
    const int w    = tid >> 6;
    const int wr   = w >> 1, wc = w & 1;
    const int fr   = lane & 15;
    const int kb   = lane >> 4;

#pragma unroll
    for (int i = 0; i < 4; ++i)
#pragma unroll
        for (int j = 0; j < 4; ++j) acc[i][j] = (f32x4){0.f, 0.f, 0.f, 0.f};

    s16x8 ra[4], rb[4];
#define LOAD_STEP(KT)                                                          \
    {                                                                          \
        int seg = (KT) >> 4;                                                   \
        int k0  = ((KT) & 15) * BKS;                                           \
        const unsigned short* Ap = (seg < 2) ? Ahi : Alo;                      \
        const unsigned short* Bp = (seg == 1) ? Blo : Bhi;                     \
        _Pragma("unroll")                                                      \
        for (int i = 0; i < 4; ++i) {                                          \
            int c = tid + (i << 8);                                            \
            int row = c >> 3, cc = (c & 7) << 3;                               \
            ra[i] = *(const s16x8*)(Ap + ((size_t)(m0 + row) << 10) + k0 + cc);\
            rb[i] = *(const s16x8*)(Bp + ((size_t)(n0 + row) << 10) + k0 + cc);\
        }                                                                      \
    }

    LOAD_STEP(0);
    for (int kt = 0; kt < 48; ++kt) {
        __syncthreads();
#pragma unroll
        for (int i = 0; i < 4; ++i) {
            int c = tid + (i << 8);
            int row = c >> 3, cc = (c & 7) << 3;
            *(s16x8*)&As[row * LDT + cc] = ra[i];
            *(s16x8*)&Bs[row * LDT + cc] = rb[i];
        }
        if (kt + 1 < 48) LOAD_STEP(kt + 1);
        __syncthreads();
#pragma unroll
        for (int kc = 0; kc < 2; ++kc) {
            s16x8 aF[4], bF[4];
#pragma unroll
            for (int i = 0; i < 4; ++i)
                aF[i] = *(const s16x8*)&As[(wr * 64 + i * 16 + fr) * LDT + kc * 32 + kb * 8];
#pragma unroll
            for (int j = 0; j < 4; ++j)
                bF[j] = *(const s16x8*)&Bs[(wc * 64 + j * 16 + fr) * LDT + kc * 32 + kb * 8];
#pragma unroll
            for (int i = 0; i < 4; ++i)
#pragma unroll
                for (int j = 0; j < 4; ++j)
                    acc[i][j] = __builtin_amdgcn_mfma_f32_16x16x32_bf16(
                        aF[i], bF[j], acc[i][j], 0, 0, 0);
        }
    }
#undef LOAD_STEP
}

// QKV: writes Q,K as bf16 hi/lo (b,h,s,d); V transposed hi/lo (b,h,d,s).
__global__ __launch_bounds__(256, 2) void qkv_mfma(
    const unsigned short* __restrict__ xhi, const unsigned short* __restrict__ xlo,
    const unsigned short* __restrict__ whi, const unsigned short* __restrict__ wlo,
    const float* __restrict__ bq, const float* __restrict__ bk,
    const float* __restrict__ bv,
    unsigned short* __restrict__ qhi, unsigned short* __restrict__ qlo,
    unsigned short* __restrict__ khi, unsigned short* __restrict__ klo,
    unsigned short* __restrict__ vthi, unsigned short* __restrict__ vtlo)
{
    const int z = blockIdx.z;
    const unsigned short* Bh = whi + ((size_t)z << 20);
    const unsigned short* Bl = wlo + ((size_t)z << 20);
    const float* bias = (z == 0) ? bq : (z == 1) ? bk : bv;
    const int m0 = blockIdx.y * BM, n0 = blockIdx.x * BN;
    f32x4 acc[4][4];
    mfma_gemm_tile(xhi, xlo, Bh, Bl, m0, n0, acc);

    const int lane = threadIdx.x & 63;
    const int w    = threadIdx.x >> 6;
    const int wr   = w >> 1, wc = w & 1;
    const int fr   = lane & 15;
    const int rg   = lane >> 4;
#pragma unroll
    for (int i = 0; i < 4; ++i)
#pragma unroll
        for (int j = 0; j < 4; ++j) {
            int n = n0 + wc * 64 + j * 16 + fr;
            int h = n >> 6, d = n & 63;
            float bv_ = bias[n];
            int m_base = m0 + wr * 64 + i * 16 + rg * 4;
            int b = m_base >> 10, s0 = m_base & 1023;
            if (z < 2) {
                unsigned short* ph = (z == 0) ? qhi : khi;
                unsigned short* pl = (z == 0) ? qlo : klo;
#pragma unroll
                for (int r = 0; r < 4; ++r) {
                    float v = acc[i][j][r] + bv_;
                    unsigned short hh = f2bf(v);
                    size_t a = ((size_t)((b * HEADS + h) * SEQ + s0 + r)) * HD + d;
                    ph[a] = hh;
                    pl[a] = f2bf(v - bf2f(hh));
                }
            } else {
                ushort4 h4, l4;
                float v0 = acc[i][j][0] + bv_;
                float v1 = acc[i][j][1] + bv_;
                float v2 = acc[i][j][2] + bv_;
                float v3 = acc[i][j][3] + bv_;
                h4.x = f2bf(v0); l4.x = f2bf(v0 - bf2f(h4.x));
                h4.y = f2bf(v1); l4.y = f2bf(v1 - bf2f(h4.y));
                h4.z = f2bf(v2); l4.z = f2bf(v2 - bf2f(h4.z));
                h4.w = f2bf(v3); l4.w = f2bf(v3 - bf2f(h4.w));
                size_t a = ((size_t)((b * HEADS + h) * HD + d)) * SEQ + s0;
                *(ushort4*)(vthi + a) = h4;
                *(ushort4*)(vtlo + a) = l4;
            }
        }
}

// OPROJ: ctx' (bf16 hi/lo) @ wo^T + bo -> out fp32  (unchanged)
__global__ __launch_bounds__(256, 2) void oproj_mfma(
    const unsigned short* __restrict__ chi, const unsigned short* __restrict__ clo,
    const unsigned short* __restrict__ whi, const unsigned short* __restrict__ wlo,
    const float* __restrict__ bo, float* __restrict__ out)
{
    const unsigned short* Bh = whi + ((size_t)3 << 20);
    const unsigned short* Bl = wlo + ((size_t)3 << 20);
    const int m0 = blockIdx.y * BM, n0 = blockIdx.x * BN;
    f32x4 acc[4][4];
    mfma_gemm_tile(chi, clo, Bh, Bl, m0, n0, acc);

    const int lane = threadIdx.x & 63;
    const int w    = threadIdx.x >> 6;
    const int wr   = w >> 1, wc = w & 1;
    const int fr   = lane & 15;
    const int rg   = lane >> 4;
#pragma unroll
    for (int i = 0; i < 4; ++i)
#pragma unroll
        for (int j = 0; j < 4; ++j) {
            int n = n0 + wc * 64 + j * 16 + fr;
            float bv_ = bo[n];
#pragma unroll
            for (int r = 0; r < 4; ++r) {
                int m = m0 + wr * 64 + i * 16 + rg * 4 + r;
                out[(size_t)m * EMB + n] = acc[i][j][r] + bv_;
            }
        }
}

// ---------------- attention: full MFMA, split-bf16 -------------------------
// Block = 16 q-rows; 4 waves; wave w owns k-cols {kt*64+16w..+16} (QK^T) and
// d-cols {16w..16w+16} (PV). Scores: 64 f32 regs/lane (MFMA C layout).
// LDS flat (ushort elems): phase1 KT hi[0,4096) lo[4096,8192);
// phase3 VT hi[0,8192) lo[8192,16384), PT hi[16384,18432) lo[18432,20480).
// All tiles XOR-swizzled: 16B-chunk ^= (row&7)  (G4/T2 fix for b128 frag reads).
__global__ __launch_bounds__(256, 3) void attn_kernel(
    const unsigned short* __restrict__ qhi, const unsigned short* __restrict__ qlo,
    const unsigned short* __restrict__ khi, const unsigned short* __restrict__ klo,
    const unsigned short* __restrict__ vthi, const unsigned short* __restrict__ vtlo,
    float* __restrict__ attn,
    unsigned short* __restrict__ chi, unsigned short* __restrict__ clo)
{
    __shared__ unsigned short SM[20480];   // 40 KB
    __shared__ float RMAX[4][16];
    __shared__ float RSUM[4][16];

    const int lid = blockIdx.y * gridDim.x + blockIdx.x;  // XCD swizzle
    const int xs  = lid & 7;
    const int jj  = lid >> 3;
    const int bh  = xs * 8 + (jj >> 6);
    const int qt  = jj & 63;

    const int tid  = threadIdx.x;
    const int w    = tid >> 6;
    const int lane = tid & 63;
    const int c    = lane & 15;
    const int g    = lane >> 4;

    const size_t bhS = (size_t)bh * SEQ;

    // Q A-frags (lane holds q-row = c, k = kd*32+g*8..+7), hi+lo
    s16x8 Qh[2], Ql[2];
    {
        size_t qb = (bhS + qt * 16 + c) * HD + g * 8;
        Qh[0] = *(const s16x8*)(qhi + qb);
        Qh[1] = *(const s16x8*)(qhi + qb + 32);
        Ql[0] = *(const s16x8*)(qlo + qb);
        Ql[1] = *(const s16x8*)(qlo + qb + 32);
    }

    f32x4 s4[16];
#pragma unroll
    for (int kt = 0; kt < 16; ++kt) s4[kt] = (f32x4){0.f, 0.f, 0.f, 0.f};

    // ---- phase 1: QK^T (split-bf16, 3 passes) ----
#pragma unroll
    for (int kt = 0; kt < 16; ++kt) {
        s16x8 st[4];
#pragma unroll
        for (int t = 0; t < 2; ++t) {
            int idx = tid + (t << 8);           // 0..511
            int row = idx >> 3, ch = idx & 7;
            size_t ga = (bhS + kt * 64 + row) * HD + ch * 8;
            st[t]     = *(const s16x8*)(khi + ga);
            st[t + 2] = *(const s16x8*)(klo + ga);
        }
        __syncthreads();   // prev tile frag reads done
#pragma unroll
        for (int t = 0; t < 2; ++t) {
            int idx = tid + (t << 8);
            int row = idx >> 3, ch = idx & 7;
            int swz = ch ^ (row & 7);
            *(s16x8*)&SM[row * 64 + swz * 8]        = st[t];
            *(s16x8*)&SM[4096 + row * 64 + swz * 8] = st[t + 2];
        }
        __syncthreads();
        const int krow = w * 16 + c;
        const int cs   = c & 7;
        s16x8 Bh0 = *(const s16x8*)&SM[krow * 64 + ((0 + g) ^ cs) * 8];
        s16x8 Bh1 = *(const s16x8*)&SM[krow * 64 + ((4 + g) ^ cs) * 8];
        s16x8 Bl0 = *(const s16x8*)&SM[4096 + krow * 64 + ((0 + g) ^ cs) * 8];
        s16x8 Bl1 = *(const s16x8*)&SM[4096 + krow * 64 + ((4 + g) ^ cs) * 8];
        s4[kt] = __builtin_amdgcn_mfma_f32_16x16x32_bf16(Qh[0], Bh0, s4[kt], 0, 0, 0);
        s4[kt] = __builtin_amdgcn_mfma_f32_16x16x32_bf16(Qh[1], Bh1, s4[kt], 0, 0, 0);
        s4[kt] = __builtin_amdgcn_mfma_f32_16x16x32_bf16(Qh[0], Bl0, s4[kt], 0, 0, 0);
        s4[kt] = __builtin_amdgcn_mfma_f32_16x16x32_bf16(Qh[1], Bl1, s4[kt], 0, 0, 0);
        s4[kt] = __builtin_amdgcn_mfma_f32_16x16x32_bf16(Ql[0], Bh0, s4[kt], 0, 0, 0);
        s4[kt] = __builtin_amdgcn_mfma_f32_16x16x32_bf16(Ql[1], Bh1, s4[kt], 0, 0, 0);
    }

    // ---- softmax ----
    float m_[4], l_[4];
#pragma unroll
    for (int r = 0; r < 4; ++r) {
        float mm = -1e30f;
#pragma unroll
        for (int kt = 0; kt < 16; ++kt) {
            s4[kt][r] *= 0.125f;
            mm = fmaxf(mm, s4[kt][r]);
        }
        m_[r] = mm;
    }
#pragma unroll
    for (int off = 1; off < 16; off <<= 1)
#pragma unroll
        for (int r = 0; r < 4; ++r) m_[r] = fmaxf(m_[r], __shfl_xor(m_[r], off));
    if (c == 0) {
#pragma unroll
        for (int r = 0; r < 4; ++r) RMAX[w][g * 4 + r] = m_[r];
    }
    __syncthreads();
#pragma unroll
    for (int r = 0; r < 4; ++r) {
        float mm = fmaxf(fmaxf(RMAX[0][g * 4 + r], RMAX[1][g * 4 + r]),
                         fmaxf(RMAX[2][g * 4 + r], RMAX[3][g * 4 + r]));
        m_[r] = mm;
    }
#pragma unroll
    for (int r = 0; r < 4; ++r) {
        float ss = 0.f;
#pragma unroll
        for (int kt = 0; kt < 16; ++kt) {
            float p = __expf(s4[kt][r] - m_[r]);
            s4[kt][r] = p;
            ss += p;
        }
        l_[r] = ss;
    }
#pragma unroll
    for (int off = 1; off < 16; off <<= 1)
#pragma unroll
        for (int r = 0; r < 4; ++r) l_[r] += __shfl_xor(l_[r], off);
    if (c == 0) {
#pragma unroll
        for (int r = 0; r < 4; ++r) RSUM[w][g * 4 + r] = l_[r];
    }
    __syncthreads();
#pragma unroll
    for (int r = 0; r < 4; ++r) {
        float ss = RSUM[0][g * 4 + r] + RSUM[1][g * 4 + r] +
                   RSUM[2][g * 4 + r] + RSUM[3][g * 4 + r];
        l_[r] = 1.f / ss;
    }

    // ---- phase 3: attn write + PV (8 chunks of 128 k) ----
    f32x4 ctx = (f32x4){0.f, 0.f, 0.f, 0.f};
    float* ap = attn + (bhS + qt * 16) * SEQ;

#pragma unroll
    for (int ct = 0; ct < 8; ++ct) {
        s16x8 vt[8];
#pragma unroll
        for (int t = 0; t < 4; ++t) {
            int idx = tid + (t << 8);          // 0..1023
            int drow = idx >> 4, ch = idx & 15;
            size_t ga = ((size_t)bh * HD + drow) * SEQ + ct * 128 + ch * 8;
            vt[t]     = *(const s16x8*)(vthi + ga);
            vt[t + 4] = *(const s16x8*)(vtlo + ga);
        }
        __syncthreads();   // prev chunk frag reads (or phase-1 KT reads) done
#pragma unroll
        for (int t = 0; t < 4; ++t) {
            int idx = tid + (t << 8);
            int drow = idx >> 4, ch = idx & 15;
            int swz = ch ^ (drow & 7);
            *(s16x8*)&SM[drow * 128 + swz * 8]        = vt[t];
            *(s16x8*)&SM[8192 + drow * 128 + swz * 8] = vt[t + 4];
        }
        // normalized P -> attn (f32 nontemporal) + PT (bf16 hi/lo, A-frag layout)
#pragma unroll
        for (int kt2 = 0; kt2 < 2; ++kt2) {
            const int ktg    = ct * 2 + kt2;
            const int klocal = kt2 * 64 + w * 16 + c;      // 0..127 in chunk
            const int chunkP = klocal >> 3;
#pragma unroll
            for (int r = 0; r < 4; ++r) {
                const int q = g * 4 + r;
                float val = s4[ktg][r] * l_[r];
                __builtin_nontemporal_store(val,
                    ap + (size_t)q * SEQ + ct * 128 + klocal);
                unsigned short hh = f2bf(val);
                unsigned short ll = f2bf(val - bf2f(hh));
                int swzP = chunkP ^ (q & 7);
                SM[16384 + q * 128 + swzP * 8 + (c & 7)] = hh;
                SM[18432 + q * 128 + swzP * 8 + (c & 7)] = ll;
            }
        }
        __syncthreads();
        // PV: wave w covers d = w*16 + c
        const int drow = w * 16 + c;
        const int ds7  = drow & 7;
        const int qs7  = c & 7;
#pragma unroll
        for (int ks = 0; ks < 4; ++ks) {
            s16x8 Pa_h = *(const s16x8*)&SM[16384 + c * 128 + ((ks * 4 + g) ^ qs7) * 8];
            s16x8 Pa_l = *(const s16x8*)&SM[18432 + c * 128 + ((ks * 4 + g) ^ qs7) * 8];
            s16x8 Vb_h = *(const s16x8*)&SM[drow * 128 + ((ks * 4 + g) ^ ds7) * 8];
            s16x8 Vb_l = *(const s16x8*)&SM[8192 + drow * 128 + ((ks * 4 + g) ^ ds7) * 8];
            ctx = __builtin_amdgcn_mfma_f32_16x16x32_bf16(Pa_h, Vb_h, ctx, 0, 0, 0);
            ctx = __builtin_amdgcn_mfma_f32_16x16x32_bf16(Pa_h, Vb_l, ctx, 0, 0, 0);
            ctx = __builtin_amdgcn_mfma_f32_16x16x32_bf16(Pa_l, Vb_h, ctx, 0, 0, 0);
        }
    }

    // ---- epilogue: ctx -> chi/clo (merged (b,s,h*d), bf16 hi/lo) ----
    {
        int b = bh >> 4, h = bh & 15;
#pragma unroll
        for (int r = 0; r < 4; ++r) {
            int qrow = qt * 16 + g * 4 + r;
            float v = ctx[r];
            unsigned short hh = f2bf(v);
            size_t a = (((size_t)(b * SEQ + qrow)) << 10) + h * HD + w * 16 + c;
            chi[a] = hh;
            clo[a] = f2bf(v - bf2f(hh));
        }
    }
}

extern "C" void kernel_launch(void* const* d_in, const int* in_sizes, int n_in,
                              void* d_out, int out_size, void* d_ws, size_t ws_size,
                              hipStream_t stream) {
    const float* x  = (const float*)d_in[0];
    const float* wq = (const float*)d_in[1];
    const float* bq = (const float*)d_in[2];
    const float* wk = (const float*)d_in[3];
    const float* bk = (const float*)d_in[4];
    const float* wv = (const float*)d_in[5];
    const float* bv = (const float*)d_in[6];
    const float* wo = (const float*)d_in[7];
    const float* bo = (const float*)d_in[8];

    float* out      = (float*)d_out;
    float* attn_out = out + (size_t)BATCH * SEQ * EMB;

    const size_t MK = (size_t)MTOT * 1024;   // 4,194,304 elems (8 MB ushort)
    unsigned short* ws16 = (unsigned short*)d_ws;
    unsigned short* xhi  = ws16;             // reused as chi after qkv
    unsigned short* xlo  = xhi + MK;         // reused as clo
    unsigned short* whi  = xlo + MK;
    unsigned short* wlo  = whi + MK;
    unsigned short* qhi  = wlo + MK;
    unsigned short* qlo  = qhi + MK;
    unsigned short* khi  = qlo + MK;
    unsigned short* klo  = khi + MK;
    unsigned short* vthi = klo + MK;
    unsigned short* vtlo = vthi + MK;        // total 80 MB (same as round 5)
    unsigned short* chi  = xhi;
    unsigned short* clo  = xlo;

    convert_x<<<MTOT, 256, 0, stream>>>(x, xhi, xlo);
    convert_w4<<<4096, 256, 0, stream>>>(wq, wk, wv, wo, whi, wlo);

    qkv_mfma<<<dim3(EMB / BN, MTOT / BM, 3), 256, 0, stream>>>(
        xhi, xlo, whi, wlo, bq, bk, bv, qhi, qlo, khi, klo, vthi, vtlo);

    attn_kernel<<<dim3(SEQ / 16, BATCH * HEADS), 256, 0, stream>>>(
        qhi, qlo, khi, klo, vthi, vtlo, attn_out, chi, clo);

    oproj_mfma<<<dim3(EMB / BN, MTOT / BM), 256, 0, stream>>>(
        chi, clo, whi, wlo, bo, out);
}